// Round 8
// baseline (1315.394 us; speedup 1.0000x reference)
//
#include <hip/hip_runtime.h>
#include <math.h>

#define N_NODE 200
#define RING   512
#define ROWF   543          // 512 + 31 mirror (odd stride -> conflict-free ring writes)
#define NSTEP  500
#define TB     32
#define NB     16           // ceil(500/32); last block kmax=20 (multiple of 4)
#define NWG    8
#define NTHR   256
#define JSL    25           // j-rows per WG slice
#define MDEP   36           // Mrec live window (mod-36 slots)
#define MROW   39           // Mrec row stride (36 slots + 3 mirror, odd)
#define HICAP  28           // d in [4,32) batch list cap (5.4 sigma)
#define LOCAP  8            // d in [0,4) per-step list cap

// ---- ws layout (float element offsets) ----
#define FPBUF   (NWG * N_NODE * TB)   // 51200 floats per parity buffer
#define OFF_FP  0                     // [2][NWG][200][32] far partials (parity by block&1)
#define OFF_BAR (2 * FPBUF)           // [64] int barrier counters
#define WS_NEED ((size_t)(2 * FPBUF + 64) * 4)

// ---- static LDS layout (byte offsets into smem[]) ----
#define SM_RED   0        // double[8]                        -> 64
#define SM_MREC  64       // float[200][39]  = 31200 B        -> 31264
#define SM_UN    31264    // float2[32][200] = 51200 B        -> 82464  (build: hi tables)
#define SM_LEDS  82464    // float[32][200]  = 25600 B        -> 108064 (build: lo tables)
#define SM_RING  108064   // float[25][543]  = 54300 B        -> 162364
#define SM_TOTAL 162364
// build-phase aliases
#define SM_HIX   SM_UN                  // u32 [28][200] = 22400
#define SM_HIW   (SM_UN + 22400)        // f32 [28][200] = 22400
#define SM_LOX   SM_LEDS                // u32 [8][200]  = 6400
#define SM_LOW   (SM_LEDS + 6400)       // f32 [8][200]  = 6400
// epilogue overlays (post-loop; below SM_RING until hEb flushed)
#define SM_LMT   64       // float[64*200]  -> 51264
#define SM_DIFF  51264    // float[200*50]  -> 91264

// ---- fast transcendentals (v_exp_f32-based, ~1e-6 rel err) ----
__device__ __forceinline__ float ftanh(float x) {
    float ax = fabsf(x);
    float t  = __expf(-2.0f * ax);
    float r  = __fdividef(1.0f - t, 1.0f + t);
    return copysignf(r, x);
}
__device__ __forceinline__ float sigm(float x) {
    return __fdividef(5.0f, 1.0f + __expf(0.56f * (6.0f - x)));
}
__device__ __forceinline__ float satf(float x) {
    return 1000.0f * ftanh(x * 0.001f);
}

__device__ __forceinline__ void grid_barrier(int* slot, int nwg) {
    __syncthreads();
    if (threadIdx.x == 0) {
        __threadfence();
        __hip_atomic_fetch_add(slot, 1, __ATOMIC_ACQ_REL, __HIP_MEMORY_SCOPE_AGENT);
        while (__hip_atomic_load(slot, __ATOMIC_ACQUIRE, __HIP_MEMORY_SCOPE_AGENT) < nwg) {
            __builtin_amdgcn_s_sleep(2);
        }
        __threadfence();
    }
    __syncthreads();
}

__global__ void zero_bar(int* bar) {
    if (threadIdx.x < 64) bar[threadIdx.x] = 0;
}

__global__ __launch_bounds__(NTHR, 1)
void jansen_b4(const float* __restrict__ inp, const float* __restrict__ noise_in,
               const float* __restrict__ hx,  const float* __restrict__ hE,
               const float* __restrict__ sc,  const float* __restrict__ wbb,
               const float* __restrict__ lm,  const int*   __restrict__ delays,
               float* __restrict__ out, float* __restrict__ ws)
{
    __shared__ char smem[SM_TOTAL];
    double*   red  = (double*)(smem + SM_RED);
    float*    Mrec = (float*)(smem + SM_MREC);
    // build-phase aliases
    unsigned* hiX  = (unsigned*)(smem + SM_HIX);
    float*    hiW  = (float*)(smem + SM_HIW);
    unsigned* loX  = (unsigned*)(smem + SM_LOX);
    float*    loW  = (float*)(smem + SM_LOW);
    // main-loop aliases
    float2*   unS  = (float2*)(smem + SM_UN);
    float*    LEdS = (float*)(smem + SM_LEDS);
    float*    ringS= (float*)(smem + SM_RING);

    const int tid = threadIdx.x;
    const int wg  = blockIdx.x;
    const int i   = tid;            // node id (active if < 200)
    const int jlo = wg * JSL;

    float* fp  = ws + OFF_FP;
    int*   bar = (int*)(ws + OFF_BAR);

    // ---- pass A: Frobenius norm of wl (redundant per WG; exact libm) ----
    double ssq = 0.0;
    for (int q = tid; q < N_NODE * N_NODE; q += NTHR) {
        int j = q / N_NODE, ii = q - j * N_NODE;
        float w1 = expf(wbb[ii * N_NODE + j]) * sc[ii * N_NODE + j];
        float w2 = expf(wbb[j * N_NODE + ii]) * sc[j * N_NODE + ii];
        float wl = log1pf(0.5f * (w1 + w2));
        ssq += (double)wl * (double)wl;
    }
    #pragma unroll
    for (int off = 32; off > 0; off >>= 1) ssq += __shfl_down(ssq, off, 64);
    if ((tid & 63) == 0) red[tid >> 6] = ssq;

    // ---- ring init: pos x holds M[-1-dd], dd=511-x; mirror [512..542] copies [0..30] ----
    for (int p = tid; p < JSL * ROWF; p += NTHR) {
        int jl = p / ROWF, x = p - jl * ROWF;
        int dd = (x < RING) ? (511 - x) : (1023 - x);
        ringS[p] = (dd < 500) ? hE[(jlo + jl) * 500 + dd] : 0.0f;
    }
    // ---- Mrec init, [node][slot] rows: M[-q] at slot 36-q (q=1..32) -> s in [4,35]:
    //      Mrec[j][s] = hE[j][35-s]; s<4 and mirror s in [36,38] = 0 ----
    for (int p = tid; p < N_NODE * MROW; p += NTHR) {
        int j = p / MROW, s = p - j * MROW;
        Mrec[p] = (s >= 4 && s < MDEP) ? hE[j * 500 + (35 - s)] : 0.0f;
    }
    // ---- zero-init near tables (padding entries: offset 0, weight 0) ----
    for (int p = tid; p < HICAP * N_NODE; p += NTHR) { hiX[p] = 0u; hiW[p] = 0.0f; }
    for (int p = tid; p < LOCAP * N_NODE; p += NTHR) { loX[p] = 0u; loW[p] = 0.0f; }
    __syncthreads();
    if (tid == 0) {
        double s = 0.0;
        #pragma unroll
        for (int r = 0; r < 8; ++r) s += red[r];
        red[0] = 1.0 / sqrt(s);
    }
    __syncthreads();
    const float inv = (float)red[0];

    // ---- pass B: near lists (lo: d<4, hi: 4<=d<32), far weights, state ----
    float rowsum = 0.0f;
    float M = 0, E = 0, I = 0, Mvv = 0, Evv = 0, Ivv = 0;
    float wreg[JSL];
    int   ereg[JSL];
    #pragma unroll
    for (int jl = 0; jl < JSL; ++jl) { wreg[jl] = 0.0f; ereg[jl] = 0; }
    int cntLo = 0, cntHi = 0;
    if (i < N_NODE) {
        for (int j = 0; j < N_NODE; ++j) {
            float w1 = expf(wbb[i * N_NODE + j]) * sc[i * N_NODE + j];
            float w2 = expf(wbb[j * N_NODE + i]) * sc[j * N_NODE + i];
            float w  = log1pf(0.5f * (w1 + w2)) * inv;
            int d = delays[j * N_NODE + i];
            rowsum += w;
            // packed entry: (j*MROW << 6) | (35 - d)
            if (d < 4) {
                if (cntLo < LOCAP) {
                    loX[cntLo * N_NODE + i] = (unsigned)((j * MROW) << 6) | (unsigned)(35 - d);
                    loW[cntLo * N_NODE + i] = w;
                    ++cntLo;
                }
            } else if (d < 32) {
                if (cntHi < HICAP) {
                    hiX[cntHi * N_NODE + i] = (unsigned)((j * MROW) << 6) | (unsigned)(35 - d);
                    hiW[cntHi * N_NODE + i] = w;
                    ++cntHi;
                }
            }
        }
        #pragma unroll
        for (int jl = 0; jl < JSL; ++jl) {
            int j = jlo + jl;
            float w1 = expf(wbb[i * N_NODE + j]) * sc[i * N_NODE + j];
            float w2 = expf(wbb[j * N_NODE + i]) * sc[j * N_NODE + i];
            float w  = log1pf(0.5f * (w1 + w2)) * inv;
            int d = delays[j * N_NODE + i];
            wreg[jl] = (d < 32) ? 0.0f : w;
            ereg[jl] = 511 - d;
        }
        M   = hx[i * 6 + 0]; E   = hx[i * 6 + 1]; I   = hx[i * 6 + 2];
        Mvv = hx[i * 6 + 3]; Evv = hx[i * 6 + 4]; Ivv = hx[i * 6 + 5];
    }

    // ---- near lists -> REGISTERS (loop-invariant; static indices only) ----
    int hix[HICAP]; float hiw[HICAP];
    int lox[LOCAP]; float low[LOCAP];
    {
        const int ii = (i < N_NODE) ? i : 0;
        #pragma unroll
        for (int n = 0; n < HICAP; ++n) {
            hix[n] = (int)hiX[n * N_NODE + ii];
            hiw[n] = hiW[n * N_NODE + ii];
        }
        #pragma unroll
        for (int z = 0; z < LOCAP; ++z) {
            lox[z] = (int)loX[z * N_NODE + ii];
            low[z] = loW[z * N_NODE + ii];
        }
    }
    __syncthreads();   // after this, table LDS reused as unS / LEdS

    const int rowM = (i < N_NODE ? i : 0) * MROW;

    // ---------------- main loop over 32-step blocks (serial phases) ----------------
    for (int b = 0; b < NB; ++b) {
        const int t0 = b * TB;
        float* fpb = fp + (b & 1) * FPBUF;

        // ---- far phase: own j-slice, contiguous mirror-padded reads ----
        if (i < N_NODE) {
            float ac[TB];
            #pragma unroll
            for (int k = 0; k < TB; ++k) ac[k] = 0.0f;
            #pragma unroll
            for (int jl = 0; jl < JSL; ++jl) {
                float w  = wreg[jl];
                int   p0 = (t0 + ereg[jl]) & 511;
                const float* rb = ringS + jl * ROWF + p0;
                #pragma unroll
                for (int k = 0; k < TB; ++k)
                    ac[k] = fmaf(w, rb[k], ac[k]);
            }
            float4* fpw = (float4*)(fpb + wg * (N_NODE * TB) + i * TB);
            #pragma unroll
            for (int q = 0; q < 8; ++q)
                fpw[q] = make_float4(ac[4*q+0], ac[4*q+1], ac[4*q+2], ac[4*q+3]);

            // ---- stage this block's u/noise to LDS as float2 (drain absorbed by barrier) ----
            #pragma unroll
            for (int k = 0; k < TB; ++k) {
                int t = t0 + k;
                float uv = 0.0f, nv = 0.0f;
                if (t < NSTEP) {
                    int bb = t / 10, h = t - 10 * bb;
                    uv = inp     [i * 500 + h * 50 + bb];
                    nv = noise_in[i * 500 + h * 50 + bb];
                }
                unS[k * N_NODE + i] = make_float2(uv, nv);
            }
        }

        grid_barrier(bar + b, NWG);

        // ---- gather partials: g-outer (per-lane row reuse), 64 float4 loads ----
        if (i < N_NODE) {
            float sA[TB];
            #pragma unroll
            for (int k = 0; k < TB; ++k) sA[k] = 0.0f;
            #pragma unroll
            for (int g = 0; g < NWG; ++g) {
                const float4* row = (const float4*)(fpb + g * (N_NODE * TB) + i * TB);
                #pragma unroll
                for (int c = 0; c < 8; ++c) {
                    float4 qv = row[c];
                    sA[4*c+0] += qv.x; sA[4*c+1] += qv.y;
                    sA[4*c+2] += qv.z; sA[4*c+3] += qv.w;
                }
            }
            #pragma unroll
            for (int k = 0; k < TB; ++k) LEdS[k * N_NODE + i] = sA[k];
        }
        __syncthreads();

        // ---- inner per-step phase, 4-step micro-batches ----
        const int kmax = (NSTEP - t0 < TB) ? (NSTEP - t0) : TB;   // 32 or 20 (mult of 4)
        int s36 = t0 % MDEP;                                      // slot of step t0+k4
        int bcur = t0 / 10, hcur = t0 - 10 * bcur;
        const bool ringw = (i >= jlo) && (i < jlo + JSL);
        const int  rbase = (i - jlo) * ROWF;
        for (int k4 = 0; k4 < kmax; k4 += 4) {
            // batch gather d in [4,32) for steps t0+k4 .. +3 (reads final data <= t-2)
            float g0 = 0, g1 = 0, g2 = 0, g3 = 0;
            if (i < N_NODE) {
                #pragma unroll
                for (int n = 0; n < 8; ++n) {
                    int tmp = (hix[n] & 63) + s36; if (tmp >= MDEP) tmp -= MDEP;
                    const float* rp = Mrec + (hix[n] >> 6) + tmp;
                    float w = hiw[n];
                    g0 = fmaf(w, rp[0], g0); g1 = fmaf(w, rp[1], g1);
                    g2 = fmaf(w, rp[2], g2); g3 = fmaf(w, rp[3], g3);
                }
                if (cntHi > 8) {
                    #pragma unroll
                    for (int n = 8; n < 16; ++n) {
                        int tmp = (hix[n] & 63) + s36; if (tmp >= MDEP) tmp -= MDEP;
                        const float* rp = Mrec + (hix[n] >> 6) + tmp;
                        float w = hiw[n];
                        g0 = fmaf(w, rp[0], g0); g1 = fmaf(w, rp[1], g1);
                        g2 = fmaf(w, rp[2], g2); g3 = fmaf(w, rp[3], g3);
                    }
                }
                if (cntHi > 16) {
                    #pragma unroll
                    for (int n = 16; n < 24; ++n) {
                        int tmp = (hix[n] & 63) + s36; if (tmp >= MDEP) tmp -= MDEP;
                        const float* rp = Mrec + (hix[n] >> 6) + tmp;
                        float w = hiw[n];
                        g0 = fmaf(w, rp[0], g0); g1 = fmaf(w, rp[1], g1);
                        g2 = fmaf(w, rp[2], g2); g3 = fmaf(w, rp[3], g3);
                    }
                }
                if (cntHi > 24) {
                    #pragma unroll
                    for (int n = 24; n < 28; ++n) {
                        int tmp = (hix[n] & 63) + s36; if (tmp >= MDEP) tmp -= MDEP;
                        const float* rp = Mrec + (hix[n] >> 6) + tmp;
                        float w = hiw[n];
                        g0 = fmaf(w, rp[0], g0); g1 = fmaf(w, rp[1], g1);
                        g2 = fmaf(w, rp[2], g2); g3 = fmaf(w, rp[3], g3);
                    }
                }
            }
            #pragma unroll
            for (int q = 0; q < 4; ++q) {
                const int k = k4 + q;
                if (i < N_NODE) {
                    int scur = s36 + q; if (scur >= MDEP) scur -= MDEP;
                    float LEd = (q == 0) ? g0 : (q == 1) ? g1 : (q == 2) ? g2 : g3;
                    LEd += LEdS[k * N_NODE + i];
                    // per-step lo band (d < 4): reads M[t-1-d], written in prior steps
                    #pragma unroll
                    for (int z = 0; z < 4; ++z) {
                        int tmp = (lox[z] & 63) + scur; if (tmp >= MDEP) tmp -= MDEP;
                        LEd = fmaf(low[z], Mrec[(lox[z] >> 6) + tmp], LEd);
                    }
                    if (cntLo > 4) {
                        #pragma unroll
                        for (int z = 4; z < 8; ++z) {
                            int tmp = (lox[z] & 63) + scur; if (tmp >= MDEP) tmp -= MDEP;
                            LEd = fmaf(low[z], Mrec[(lox[z] >> 6) + tmp], LEd);
                        }
                    }
                    float2 un = unS[k * N_NODE + i];
                    float u  = un.x;
                    float nz = un.y;
                    float rM = sigm(E - I);
                    float rE = 250.0f * nz + 1000.01f * (LEd - rowsum * E) + 108.01f * sigm(135.01f * M);
                    float rI = 33.76f * sigm(33.76f * M);
                    float ddM = M + 1e-4f * Mvv;
                    float ddE = E + 1e-4f * Evv;
                    float ddI = I + 1e-4f * Ivv;
                    float uu  = u + 500.0f * ftanh(rM * 0.002f);
                    float ddMv = Mvv + 1e-4f * (328.25f * uu - 202.0f * Mvv - 10201.0f * M);
                    float uE  = 500.0f * ftanh(rE * 0.002f);
                    float ddEv = Evv + 1e-4f * (328.25f * uE - 202.0f * Evv - 10201.0f * E);
                    float uI  = 500.0f * ftanh(rI * 0.002f);
                    float ddIv = Ivv + 1e-4f * (1122.0f * uI - 102.0f * Ivv - 2601.0f * I);
                    M   = satf(ddM);  E   = satf(ddE);  I   = satf(ddI);
                    Mvv = satf(ddMv); Evv = satf(ddEv); Ivv = satf(ddIv);
                    // publish M: row layout + mirror dup (slots 36..38 = copies of 0..2)
                    Mrec[rowM + scur] = M;
                    if (scur < 3) Mrec[rowM + scur + MDEP] = M;
                    if (ringw) {
                        int pt = (t0 + k) & 511;
                        ringS[rbase + pt] = M;
                        if (pt < 31) ringS[rbase + pt + 512] = M;
                    }
                    if (wg == 0 && hcur == 9) {
                        out[ 4400 + i * 50 + bcur] = E;
                        out[14400 + i * 50 + bcur] = I;
                        out[24400 + i * 50 + bcur] = M;
                        out[34400 + i * 50 + bcur] = Evv;
                        out[44400 + i * 50 + bcur] = Ivv;
                        out[54400 + i * 50 + bcur] = Mvv;
                    }
                    ++hcur; if (hcur == 10) { hcur = 0; ++bcur; }
                }
                __syncthreads();
            }
            s36 += 4; if (s36 >= MDEP) s36 -= MDEP;
        }
    }

    // ---------------- epilogue ----------------
    // hEb slice: rows [jlo, jlo+JSL) from LDS ring
    for (int p = tid; p < JSL * 500; p += NTHR) {
        int jl = p / 500, dd = p - jl * 500;
        out[64400 + (jlo + jl) * 500 + dd] = ringS[jl * ROWF + ((499 - dd) & 511)];
    }
    if (wg != 0) return;

    if (i < N_NODE) {
        out[3200 + i * 6 + 0] = M;
        out[3200 + i * 6 + 1] = E;
        out[3200 + i * 6 + 2] = I;
        out[3200 + i * 6 + 3] = Mvv;
        out[3200 + i * 6 + 4] = Evv;
        out[3200 + i * 6 + 5] = Ivv;
    }

    float* lmt  = (float*)(smem + SM_LMT);
    float* diff = (float*)(smem + SM_DIFF);
    __syncthreads();
    if (tid < 64) {
        float s = 0.0f;
        for (int n = 0; n < N_NODE; ++n) { float v = lm[tid * N_NODE + n]; s += v * v; }
        float ivn = 1.0f / sqrtf(s);
        for (int n = 0; n < N_NODE; ++n) lmt[tid * N_NODE + n] = lm[tid * N_NODE + n] * ivn;
    }
    __syncthreads();
    if (tid < N_NODE) {
        float s = 0.0f;
        for (int o = 0; o < 64; ++o) s += lmt[o * N_NODE + tid];
        s *= (1.0f / 64.0f);
        for (int o = 0; o < 64; ++o) lmt[o * N_NODE + tid] -= s;
    }
    __syncthreads();
    for (int p = tid; p < 10000; p += NTHR) diff[p] = out[4400 + p] - out[14400 + p];
    __syncthreads();
    for (int p = tid; p < 3200; p += NTHR) {
        int o = p / 50, bb = p - o * 50;
        float s = 0.0f;
        for (int n = 0; n < N_NODE; ++n)
            s = fmaf(lmt[o * N_NODE + n], diff[n * 50 + bb], s);
        out[p] = 5.0f * s - 2.0f;
    }
}

// ---------------- fallback: single-WG kernel ----------------
__global__ __launch_bounds__(1024, 1)
void jansen_main(const float* __restrict__ inp, const float* __restrict__ noise_in,
                 const float* __restrict__ hx,  const float* __restrict__ hE,
                 const float* __restrict__ sc,  const float* __restrict__ wbb,
                 const float* __restrict__ lm,  const int*   __restrict__ delays,
                 float* __restrict__ out, float* __restrict__ ws)
{
    const int tid = threadIdx.x;
    const int i   = tid & 255;
    const int c   = tid >> 8;

    float* ring = ws;
    float* lmt  = ws + N_NODE * RING;

    __shared__ double red[18];
    __shared__ float  part[4][N_NODE];
    __shared__ float  wn[N_NODE * N_NODE];

    double ssq = 0.0;
    for (int p = tid; p < N_NODE * N_NODE; p += 1024) {
        int r0 = p / N_NODE;
        int cc = p - r0 * N_NODE;
        float w1 = expf(wbb[p]) * sc[p];
        float w2 = expf(wbb[cc * N_NODE + r0]) * sc[cc * N_NODE + r0];
        float v  = log1pf(0.5f * (w1 + w2));
        wn[p] = v;
        ssq += (double)v * (double)v;
    }
    #pragma unroll
    for (int off = 32; off > 0; off >>= 1) ssq += __shfl_down(ssq, off, 64);
    if ((tid & 63) == 0) red[tid >> 6] = ssq;
    __syncthreads();
    if (tid == 0) {
        double s = 0.0;
        for (int k = 0; k < 16; ++k) s += red[k];
        red[16] = 1.0 / sqrt(s);
    }
    __syncthreads();
    const float inv_norm = (float)red[16];
    for (int p = tid; p < N_NODE * N_NODE; p += 1024) wn[p] *= inv_norm;

    for (int p = tid; p < N_NODE * 500; p += 1024) {
        int j = p / 500, dd = p - j * 500;
        ring[j * RING + (511 - dd)] = hE[p];
    }
    if (tid < 64) {
        float s = 0.0f;
        for (int n = 0; n < N_NODE; ++n) { float v = lm[tid * N_NODE + n]; s += v * v; }
        float inv = 1.0f / sqrtf(s);
        for (int n = 0; n < N_NODE; ++n) lmt[tid * N_NODE + n] = lm[tid * N_NODE + n] * inv;
    }
    __syncthreads();
    if (tid < N_NODE) {
        float s = 0.0f;
        for (int o = 0; o < 64; ++o) s += lmt[o * N_NODE + tid];
        s *= (1.0f / 64.0f);
        for (int o = 0; o < 64; ++o) lmt[o * N_NODE + tid] -= s;
    }

    unsigned int dpk[25];
    if (i < N_NODE) {
        #pragma unroll
        for (int r0 = 0; r0 < 25; ++r0) {
            int d0 = delays[(c * 50 + 2 * r0    ) * N_NODE + i];
            int d1 = delays[(c * 50 + 2 * r0 + 1) * N_NODE + i];
            unsigned e0 = (unsigned)((-1 - d0) & 511);
            unsigned e1 = (unsigned)((-1 - d1) & 511);
            dpk[r0] = e0 | (e1 << 16);
        }
    }

    float M = 0, E = 0, I = 0, Mvv = 0, Evv = 0, Ivv = 0, rowsum = 0;
    if (c == 0 && i < N_NODE) {
        M   = hx[i * 6 + 0]; E   = hx[i * 6 + 1]; I   = hx[i * 6 + 2];
        Mvv = hx[i * 6 + 3]; Evv = hx[i * 6 + 4]; Ivv = hx[i * 6 + 5];
    }
    __syncthreads();
    if (c == 0 && i < N_NODE) {
        float s = 0.0f;
        for (int j = 0; j < N_NODE; ++j) s += wn[j * N_NODE + i];
        rowsum = s;
    }

    for (int t = 0; t < NSTEP; ++t) {
        if (i < N_NODE) {
            float acc = 0.0f;
            const float* ringc = ring + c * 50 * RING;
            const float* wnc   = wn + c * 50 * N_NODE + i;
            #pragma unroll
            for (int r0 = 0; r0 < 50; ++r0) {
                unsigned e = (dpk[r0 >> 1] >> ((r0 & 1) << 4)) & 0xffffu;
                int pos = (int)(((unsigned)t + e) & 511u);
                acc = fmaf(wnc[r0 * N_NODE], ringc[r0 * RING + pos], acc);
            }
            part[c][i] = acc;
        }
        __syncthreads();
        if (c == 0 && i < N_NODE) {
            float LEd = part[0][i] + part[1][i] + part[2][i] + part[3][i];
            int b = t / 10, h = t - b * 10;
            float u  = inp     [i * 500 + h * 50 + b];
            float nz = noise_in[i * 500 + h * 50 + b];
            float rM = 5.0f / (1.0f + expf(0.56f * (6.0f - (E - I))));
            float rE = 250.0f * nz + 1000.01f * (LEd - rowsum * E) + 108.01f * (5.0f / (1.0f + expf(0.56f * (6.0f - 135.01f * M))));
            float rI = 33.76f * (5.0f / (1.0f + expf(0.56f * (6.0f - 33.76f * M))));
            float ddM = M + 1e-4f * Mvv;
            float ddE = E + 1e-4f * Evv;
            float ddI = I + 1e-4f * Ivv;
            float uu  = u + 500.0f * tanhf(rM / 500.0f);
            float ddMv = Mvv + 1e-4f * (328.25f * uu - 202.0f * Mvv - 10201.0f * M);
            float uE  = 500.0f * tanhf(rE / 500.0f);
            float ddEv = Evv + 1e-4f * (328.25f * uE - 202.0f * Evv - 10201.0f * E);
            float uI  = 500.0f * tanhf(rI / 500.0f);
            float ddIv = Ivv + 1e-4f * (1122.0f * uI - 102.0f * Ivv - 2601.0f * I);
            M   = 1000.0f * tanhf(ddM / 1000.0f);
            E   = 1000.0f * tanhf(ddE / 1000.0f);
            I   = 1000.0f * tanhf(ddI / 1000.0f);
            Mvv = 1000.0f * tanhf(ddMv / 1000.0f);
            Evv = 1000.0f * tanhf(ddEv / 1000.0f);
            Ivv = 1000.0f * tanhf(ddIv / 1000.0f);
            ring[i * RING + (t & 511)] = M;
            if (h == 9) {
                out[ 4400 + i * 50 + b] = E;
                out[14400 + i * 50 + b] = I;
                out[24400 + i * 50 + b] = M;
                out[34400 + i * 50 + b] = Evv;
                out[44400 + i * 50 + b] = Ivv;
                out[54400 + i * 50 + b] = Mvv;
            }
        }
        __syncthreads();
    }

    if (c == 0 && i < N_NODE) {
        out[3200 + i * 6 + 0] = M;
        out[3200 + i * 6 + 1] = E;
        out[3200 + i * 6 + 2] = I;
        out[3200 + i * 6 + 3] = Mvv;
        out[3200 + i * 6 + 4] = Evv;
        out[3200 + i * 6 + 5] = Ivv;
    }
    for (int p = tid; p < N_NODE * 500; p += 1024) {
        int ii = p / 500, dd = p - ii * 500;
        out[64400 + p] = ring[ii * RING + (499 - dd)];
    }
    __syncthreads();
    for (int p = tid; p < 64 * 50; p += 1024) {
        int o = p / 50, b = p - o * 50;
        float s = 0.0f;
        for (int n = 0; n < N_NODE; ++n)
            s += lmt[o * N_NODE + n] * (out[4400 + n * 50 + b] - out[14400 + n * 50 + b]);
        out[p] = 5.0f * s - 2.0f;
    }
}

extern "C" void kernel_launch(void* const* d_in, const int* in_sizes, int n_in,
                              void* d_out, int out_size, void* d_ws, size_t ws_size,
                              hipStream_t stream) {
    if (ws_size >= WS_NEED) {
        zero_bar<<<1, 64, 0, stream>>>((int*)((float*)d_ws + OFF_BAR));
        jansen_b4<<<NWG, NTHR, 0, stream>>>(
            (const float*)d_in[0], (const float*)d_in[1], (const float*)d_in[2],
            (const float*)d_in[3], (const float*)d_in[4], (const float*)d_in[5],
            (const float*)d_in[6], (const int*)d_in[7],
            (float*)d_out, (float*)d_ws);
    } else {
        jansen_main<<<1, 1024, 0, stream>>>(
            (const float*)d_in[0], (const float*)d_in[1], (const float*)d_in[2],
            (const float*)d_in[3], (const float*)d_in[4], (const float*)d_in[5],
            (const float*)d_in[6], (const int*)d_in[7],
            (float*)d_out, (float*)d_ws);
    }
}